// Round 15
// baseline (281.913 us; speedup 1.0000x reference)
//
#include <hip/hip_runtime.h>
#include <hip/hip_fp16.h>

#define N_NODES 50000
#define NFEAT 64
#define NB_BUCKETS ((N_NODES + 255) / 256)  // 196 coarse buckets (dst >> 8)
#define CHUNK 4096                          // edges per block in build passes

#define FMA4(A, S, V)                                                          \
    do {                                                                       \
        A.x = fmaf(S, V.x, A.x);                                               \
        A.y = fmaf(S, V.y, A.y);                                               \
        A.z = fmaf(S, V.z, A.z);                                               \
        A.w = fmaf(S, V.w, A.w);                                               \
    } while (0)

// ---------------- CSR build: 2-pass counting sort, coalesced writes ----------------

__global__ __launch_bounds__(256) void k_bhist(const int* __restrict__ dst, int E,
                                               int* __restrict__ bucketCount) {
    __shared__ int cnt[NB_BUCKETS];
    for (int i = threadIdx.x; i < NB_BUCKETS; i += 256) cnt[i] = 0;
    __syncthreads();
    int cbeg = blockIdx.x * CHUNK;
    int cend = min(cbeg + CHUNK, E);
    for (int e = cbeg + threadIdx.x; e < cend; e += 256)
        atomicAdd(&cnt[dst[e] >> 8], 1);
    __syncthreads();
    for (int i = threadIdx.x; i < NB_BUCKETS; i += 256)
        if (cnt[i]) atomicAdd(&bucketCount[i], cnt[i]);
}

// One tiny block: exclusive scan of 196 bucket counts.
__global__ __launch_bounds__(256) void k_bscan(const int* __restrict__ bucketCount,
                                               int E, int* __restrict__ bucketBase,
                                               int* __restrict__ bucketCursor,
                                               int* __restrict__ offs) {
    __shared__ int s[256];
    int t = threadIdx.x;
    int v = (t < NB_BUCKETS) ? bucketCount[t] : 0;
    s[t] = v;
    __syncthreads();
    for (int off = 1; off < 256; off <<= 1) {
        int u = (t >= off) ? s[t - off] : 0;
        __syncthreads();
        if (t >= off) s[t] += u;
        __syncthreads();
    }
    if (t < NB_BUCKETS) {
        int b = s[t] - v;
        bucketBase[t] = b;
        bucketCursor[t] = b;
    }
    if (t == 0) {
        bucketBase[NB_BUCKETS] = E;
        offs[N_NODES] = E;
    }
}

// Place edges into bucket-major tmp; block-private contiguous ranges avoid
// cross-XCD dirty-line duplication (measured 8x write amp with naive scatter).
__global__ __launch_bounds__(256) void k_bplace(const int* __restrict__ src,
                                                const int* __restrict__ dst,
                                                const float* __restrict__ w, int E,
                                                int* __restrict__ bucketCursor,
                                                int2* __restrict__ tmp) {
    __shared__ int cnt[NB_BUCKETS];
    __shared__ int base[NB_BUCKETS];
    for (int i = threadIdx.x; i < NB_BUCKETS; i += 256) cnt[i] = 0;
    __syncthreads();
    int cbeg = blockIdx.x * CHUNK;
    int cend = min(cbeg + CHUNK, E);
    for (int e = cbeg + threadIdx.x; e < cend; e += 256)
        atomicAdd(&cnt[dst[e] >> 8], 1);
    __syncthreads();
    for (int i = threadIdx.x; i < NB_BUCKETS; i += 256) {
        int c = cnt[i];
        base[i] = c ? atomicAdd(&bucketCursor[i], c) : 0;
        cnt[i] = 0;  // reuse as intra-block cursor
    }
    __syncthreads();
    for (int e = cbeg + threadIdx.x; e < cend; e += 256) {
        int d = dst[e];
        int b = d >> 8;
        int r = atomicAdd(&cnt[b], 1);
        tmp[base[b] + r] = make_int2(((d & 255) << 16) | src[e], __float_as_int(w[e]));
    }
}

// One block per bucket: 256-way counting sort by dst&255 fully in LDS.
__global__ __launch_bounds__(256) void k_bsort(const int* __restrict__ bucketBase,
                                               const int2* __restrict__ tmp,
                                               int2* __restrict__ pairs,
                                               int* __restrict__ offs) {
    __shared__ int cnt[256];
    __shared__ int ex[256];
    int b = blockIdx.x;
    int t = threadIdx.x;
    int beg = bucketBase[b], end = bucketBase[b + 1];
    cnt[t] = 0;
    __syncthreads();
    for (int e = beg + t; e < end; e += 256)
        atomicAdd(&cnt[(tmp[e].x >> 16) & 255], 1);
    __syncthreads();
    int v = cnt[t];
    ex[t] = v;
    __syncthreads();
    for (int off = 1; off < 256; off <<= 1) {
        int u = (t >= off) ? ex[t - off] : 0;
        __syncthreads();
        if (t >= off) ex[t] += u;
        __syncthreads();
    }
    int myex = ex[t] - v;
    int d = (b << 8) + t;
    if (d < N_NODES) offs[d] = beg + myex;
    cnt[t] = myex;
    __syncthreads();
    for (int e = beg + t; e < end; e += 256) {
        int2 kv = tmp[e];
        int c = (kv.x >> 16) & 255;
        int r = atomicAdd(&cnt[c], 1);
        pairs[beg + r] = make_int2(kv.x & 0xFFFF, kv.y);
    }
}

// ---------------- fp32 -> fp16 convert ----------------

__global__ __launch_bounds__(256) void k_f2h(const float* __restrict__ in,
                                             __half* __restrict__ out, int n4) {
    int i = blockIdx.x * 256 + threadIdx.x;  // one float4 per thread
    if (i >= n4) return;
    float4 v = ((const float4*)in)[i];
    float2 packed;
    ((__half2*)&packed)[0] = __float22half2_rn(make_float2(v.x, v.y));
    ((__half2*)&packed)[1] = __float22half2_rn(make_float2(v.z, v.w));
    ((float2*)out)[i] = packed;
}

// ---------------- SpMM, feature-split: 2 passes x 32 feats ----------------
// Each pass touches ONE 64B line per gathered row -> working set 3.2 MB < 4 MiB
// per-XCD L2 -> gathers become L2 hits. pairs reads + fp16 writes are
// non-temporal so the streaming traffic doesn't evict the gather set.
// 4 nodes/wave, 16 lanes/node, 2 feats (half2) per lane; fp32 accumulate.

template <bool OUT_HALF>
__global__ __launch_bounds__(256) void k_spmm2h(const int* __restrict__ offs,
                                                const int2* __restrict__ pairs,
                                                const __half* __restrict__ Hin,
                                                void* __restrict__ Hout_,
                                                int fbase) {
    int tid = blockIdx.x * 256 + threadIdx.x;
    int wave = tid >> 6;
    int lane = threadIdx.x & 63;
    int node = wave * 4 + (lane >> 4);  // 4 nodes per wave
    int q = lane & 15;                  // 2 feats: fbase+2q, fbase+2q+1
    if (node >= N_NODES) return;
    int beg = offs[node], end = offs[node + 1];
    const __half* hbase = Hin + fbase + 2 * q;
    float2 a0 = {0.f, 0.f}, a1 = {0.f, 0.f}, a2 = {0.f, 0.f}, a3 = {0.f, 0.f};
    int e = beg;
    for (; e + 4 <= end; e += 4) {  // 4 gathers in flight
        long long v0 = __builtin_nontemporal_load((const long long*)(pairs + e));
        long long v1 = __builtin_nontemporal_load((const long long*)(pairs + e + 1));
        long long v2 = __builtin_nontemporal_load((const long long*)(pairs + e + 2));
        long long v3 = __builtin_nontemporal_load((const long long*)(pairs + e + 3));
        float2 f0 = __half22float2(*(const __half2*)(hbase + (size_t)(int)v0 * NFEAT));
        float2 f1 = __half22float2(*(const __half2*)(hbase + (size_t)(int)v1 * NFEAT));
        float2 f2 = __half22float2(*(const __half2*)(hbase + (size_t)(int)v2 * NFEAT));
        float2 f3 = __half22float2(*(const __half2*)(hbase + (size_t)(int)v3 * NFEAT));
        float w0 = __int_as_float((int)(v0 >> 32));
        float w1 = __int_as_float((int)(v1 >> 32));
        float w2 = __int_as_float((int)(v2 >> 32));
        float w3 = __int_as_float((int)(v3 >> 32));
        a0.x = fmaf(w0, f0.x, a0.x);
        a0.y = fmaf(w0, f0.y, a0.y);
        a1.x = fmaf(w1, f1.x, a1.x);
        a1.y = fmaf(w1, f1.y, a1.y);
        a2.x = fmaf(w2, f2.x, a2.x);
        a2.y = fmaf(w2, f2.y, a2.y);
        a3.x = fmaf(w3, f3.x, a3.x);
        a3.y = fmaf(w3, f3.y, a3.y);
    }
    for (; e < end; ++e) {
        long long v = __builtin_nontemporal_load((const long long*)(pairs + e));
        float2 f = __half22float2(*(const __half2*)(hbase + (size_t)(int)v * NFEAT));
        float w = __int_as_float((int)(v >> 32));
        a0.x = fmaf(w, f.x, a0.x);
        a0.y = fmaf(w, f.y, a0.y);
    }
    float ax = (a0.x + a1.x) + (a2.x + a3.x);
    float ay = (a0.y + a1.y) + (a2.y + a3.y);
    if constexpr (OUT_HALF) {
        __half2 o = __float22half2_rn(make_float2(ax, ay));
        unsigned uo = *reinterpret_cast<unsigned*>(&o);
        __builtin_nontemporal_store(
            uo, (unsigned*)((__half*)Hout_ + (size_t)node * NFEAT + fbase + 2 * q));
    } else {
        // fp32 output feeds k_gemm immediately -> keep it cached (no NT).
        *(float2*)((float*)Hout_ + (size_t)node * NFEAT + fbase + 2 * q) =
            make_float2(ax, ay);
    }
}

// ---------------- Dense epilogue: out = H @ W + b (fp32, vector ALU) ----------------

__global__ __launch_bounds__(256) void k_gemm(const float* __restrict__ Hin,
                                              const float* __restrict__ W,
                                              const float* __restrict__ b,
                                              float* __restrict__ out) {
    __shared__ float4 WL[64 * 16];  // 16 KiB
    __shared__ float4 BL[16];
    int t = threadIdx.x;
    const float4* W4 = (const float4*)W;
    for (int k = t; k < 1024; k += 256) WL[k] = W4[k];
    if (t < 16) BL[t] = ((const float4*)b)[t];
    __syncthreads();
    int n = blockIdx.x * 256 + t;  // one node per thread
    if (n >= N_NODES) return;
    const float4* Hrow = (const float4*)(Hin + (size_t)n * NFEAT);
    float4 acc[16];
#pragma unroll
    for (int j = 0; j < 16; ++j) acc[j] = BL[j];
    for (int i4 = 0; i4 < 16; ++i4) {
        float4 h = Hrow[i4];
        const float4* w0 = &WL[(i4 * 4 + 0) * 16];
        const float4* w1 = &WL[(i4 * 4 + 1) * 16];
        const float4* w2 = &WL[(i4 * 4 + 2) * 16];
        const float4* w3 = &WL[(i4 * 4 + 3) * 16];
#pragma unroll
        for (int j = 0; j < 16; ++j) {
            FMA4(acc[j], h.x, w0[j]);
            FMA4(acc[j], h.y, w1[j]);
            FMA4(acc[j], h.z, w2[j]);
            FMA4(acc[j], h.w, w3[j]);
        }
    }
    float4* o = (float4*)(out + (size_t)n * NFEAT);
#pragma unroll
    for (int j = 0; j < 16; ++j) o[j] = acc[j];
}

// ---------------- launch ----------------

extern "C" void kernel_launch(void* const* d_in, const int* in_sizes, int n_in,
                              void* d_out, int out_size, void* d_ws, size_t ws_size,
                              hipStream_t stream) {
    const int* edge_index = (const int*)d_in[0];
    const float* ew = (const float*)d_in[1];
    const float* H = (const float*)d_in[2];
    const float* W = (const float*)d_in[3];
    const float* b = (const float*)d_in[4];
    float* out = (float*)d_out;

    int E = in_sizes[1];              // 800000
    const int* src = edge_index;      // [2,E] row-major: row 0 = src
    const int* dst = edge_index + E;  // row 1 = dst

    // workspace carve-out
    char* ws = (char*)d_ws;
    size_t off = 0;
    auto alloc = [&](size_t bytes) -> void* {
        void* p = ws + off;
        off += (bytes + 255) & ~(size_t)255;
        return p;
    };
    int* bucketCount = (int*)alloc((size_t)NB_BUCKETS * 4);
    int* bucketBase = (int*)alloc(((size_t)NB_BUCKETS + 1) * 4);
    int* bucketCursor = (int*)alloc((size_t)NB_BUCKETS * 4);
    int* offs = (int*)alloc(((size_t)N_NODES + 1) * 4);
    int2* tmp = (int2*)alloc((size_t)E * 8);
    int2* pairs = (int2*)alloc((size_t)E * 8);
    __half* h0 = (__half*)alloc((size_t)N_NODES * NFEAT * 2);  // fp16 ping
    __half* h1 = (__half*)alloc((size_t)N_NODES * NFEAT * 2);  // fp16 pong
    float* bufA = (float*)alloc((size_t)N_NODES * NFEAT * 4);  // fp32 H3

    hipMemsetAsync(bucketCount, 0, (size_t)NB_BUCKETS * 4, stream);

    int nch = (E + CHUNK - 1) / CHUNK;  // 196
    k_bhist<<<nch, 256, 0, stream>>>(dst, E, bucketCount);
    k_bscan<<<1, 256, 0, stream>>>(bucketCount, E, bucketBase, bucketCursor, offs);
    k_bplace<<<nch, 256, 0, stream>>>(src, dst, ew, E, bucketCursor, tmp);
    k_bsort<<<NB_BUCKETS, 256, 0, stream>>>(bucketBase, tmp, pairs, offs);

    // H (fp32) -> h0 (fp16)
    int n4 = N_NODES * NFEAT / 4;  // 800000 float4s
    k_f2h<<<(n4 + 255) / 256, 256, 0, stream>>>(H, h0, n4);

    int nb = (N_NODES + 15) / 16;  // 3125 blocks, 16 nodes/block
    // Layer 1: h0 -> h1, two feature-half passes (L2-resident working set)
    k_spmm2h<true><<<nb, 256, 0, stream>>>(offs, pairs, h0, h1, 0);
    k_spmm2h<true><<<nb, 256, 0, stream>>>(offs, pairs, h0, h1, 32);
    // Layer 2: h1 -> h0
    k_spmm2h<true><<<nb, 256, 0, stream>>>(offs, pairs, h1, h0, 0);
    k_spmm2h<true><<<nb, 256, 0, stream>>>(offs, pairs, h1, h0, 32);
    // Layer 3: h0 -> bufA (fp32)
    k_spmm2h<false><<<nb, 256, 0, stream>>>(offs, pairs, h0, bufA, 0);
    k_spmm2h<false><<<nb, 256, 0, stream>>>(offs, pairs, h0, bufA, 32);

    k_gemm<<<(N_NODES + 255) / 256, 256, 0, stream>>>(bufA, W, b, out);
}

// Round 17
// 214.405 us; speedup vs baseline: 1.3149x; 1.3149x over previous
//
#include <hip/hip_runtime.h>
#include <hip/hip_fp16.h>

#define N_NODES 50000
#define NFEAT 64
#define NB_BUCKETS ((N_NODES + 255) / 256)  // 196 coarse buckets (dst >> 8)
#define CHUNK 4096                          // edges per block in build passes

#define FMA4(A, S, V)                                                          \
    do {                                                                       \
        A.x = fmaf(S, V.x, A.x);                                               \
        A.y = fmaf(S, V.y, A.y);                                               \
        A.z = fmaf(S, V.z, A.z);                                               \
        A.w = fmaf(S, V.w, A.w);                                               \
    } while (0)

// ---------------- CSR build: 2-pass counting sort, coalesced writes ----------------

__global__ __launch_bounds__(256) void k_bhist(const int* __restrict__ dst, int E,
                                               int* __restrict__ bucketCount) {
    __shared__ int cnt[NB_BUCKETS];
    for (int i = threadIdx.x; i < NB_BUCKETS; i += 256) cnt[i] = 0;
    __syncthreads();
    int cbeg = blockIdx.x * CHUNK;
    int cend = min(cbeg + CHUNK, E);
    for (int e = cbeg + threadIdx.x; e < cend; e += 256)
        atomicAdd(&cnt[dst[e] >> 8], 1);
    __syncthreads();
    for (int i = threadIdx.x; i < NB_BUCKETS; i += 256)
        if (cnt[i]) atomicAdd(&bucketCount[i], cnt[i]);
}

// One tiny block: exclusive scan of 196 bucket counts.
__global__ __launch_bounds__(256) void k_bscan(const int* __restrict__ bucketCount,
                                               int E, int* __restrict__ bucketBase,
                                               int* __restrict__ bucketCursor,
                                               int* __restrict__ offs) {
    __shared__ int s[256];
    int t = threadIdx.x;
    int v = (t < NB_BUCKETS) ? bucketCount[t] : 0;
    s[t] = v;
    __syncthreads();
    for (int off = 1; off < 256; off <<= 1) {
        int u = (t >= off) ? s[t - off] : 0;
        __syncthreads();
        if (t >= off) s[t] += u;
        __syncthreads();
    }
    if (t < NB_BUCKETS) {
        int b = s[t] - v;
        bucketBase[t] = b;
        bucketCursor[t] = b;
    }
    if (t == 0) {
        bucketBase[NB_BUCKETS] = E;
        offs[N_NODES] = E;
    }
}

// Place edges into bucket-major tmp; block-private contiguous ranges avoid
// cross-XCD dirty-line duplication (measured 8x write amp with naive scatter).
__global__ __launch_bounds__(256) void k_bplace(const int* __restrict__ src,
                                                const int* __restrict__ dst,
                                                const float* __restrict__ w, int E,
                                                int* __restrict__ bucketCursor,
                                                int2* __restrict__ tmp) {
    __shared__ int cnt[NB_BUCKETS];
    __shared__ int base[NB_BUCKETS];
    for (int i = threadIdx.x; i < NB_BUCKETS; i += 256) cnt[i] = 0;
    __syncthreads();
    int cbeg = blockIdx.x * CHUNK;
    int cend = min(cbeg + CHUNK, E);
    for (int e = cbeg + threadIdx.x; e < cend; e += 256)
        atomicAdd(&cnt[dst[e] >> 8], 1);
    __syncthreads();
    for (int i = threadIdx.x; i < NB_BUCKETS; i += 256) {
        int c = cnt[i];
        base[i] = c ? atomicAdd(&bucketCursor[i], c) : 0;
        cnt[i] = 0;  // reuse as intra-block cursor
    }
    __syncthreads();
    for (int e = cbeg + threadIdx.x; e < cend; e += 256) {
        int d = dst[e];
        int b = d >> 8;
        int r = atomicAdd(&cnt[b], 1);
        tmp[base[b] + r] = make_int2(((d & 255) << 16) | src[e], __float_as_int(w[e]));
    }
}

// One block per bucket: 256-way counting sort by dst&255 fully in LDS.
__global__ __launch_bounds__(256) void k_bsort(const int* __restrict__ bucketBase,
                                               const int2* __restrict__ tmp,
                                               int2* __restrict__ pairs,
                                               int* __restrict__ offs) {
    __shared__ int cnt[256];
    __shared__ int ex[256];
    int b = blockIdx.x;
    int t = threadIdx.x;
    int beg = bucketBase[b], end = bucketBase[b + 1];
    cnt[t] = 0;
    __syncthreads();
    for (int e = beg + t; e < end; e += 256)
        atomicAdd(&cnt[(tmp[e].x >> 16) & 255], 1);
    __syncthreads();
    int v = cnt[t];
    ex[t] = v;
    __syncthreads();
    for (int off = 1; off < 256; off <<= 1) {
        int u = (t >= off) ? ex[t - off] : 0;
        __syncthreads();
        if (t >= off) ex[t] += u;
        __syncthreads();
    }
    int myex = ex[t] - v;
    int d = (b << 8) + t;
    if (d < N_NODES) offs[d] = beg + myex;
    cnt[t] = myex;
    __syncthreads();
    for (int e = beg + t; e < end; e += 256) {
        int2 kv = tmp[e];
        int c = (kv.x >> 16) & 255;
        int r = atomicAdd(&cnt[c], 1);
        pairs[beg + r] = make_int2(kv.x & 0xFFFF, kv.y);
    }
}

// ---------------- fp32 -> fp16 convert ----------------

__global__ __launch_bounds__(256) void k_f2h(const float* __restrict__ in,
                                             __half* __restrict__ out, int n4) {
    int i = blockIdx.x * 256 + threadIdx.x;  // one float4 per thread
    if (i >= n4) return;
    float4 v = ((const float4*)in)[i];
    float2 packed;
    ((__half2*)&packed)[0] = __float22half2_rn(make_float2(v.x, v.y));
    ((__half2*)&packed)[1] = __float22half2_rn(make_float2(v.z, v.w));
    ((float2*)out)[i] = packed;
}

// ---------------- SpMM: 4 nodes/wave, 16 lanes x 4 feats; fp16 gathers ----------------
// R14 structure (best known) + deeper ILP: 4 gathers in flight per 16-lane
// group, and pairs consumed as int4 (2 edges / 16B load, alignment prologue).

template <bool OUT_HALF>
__global__ __launch_bounds__(256) void k_spmm4h(const int* __restrict__ offs,
                                                const int2* __restrict__ pairs,
                                                const __half* __restrict__ Hin,
                                                void* __restrict__ Hout_) {
    int tid = blockIdx.x * 256 + threadIdx.x;
    int wave = tid >> 6;
    int lane = threadIdx.x & 63;
    int node = wave * 4 + (lane >> 4);  // 4 nodes per wave
    int q = lane & 15;                  // features [4q..4q+3]
    if (node >= N_NODES) return;
    int beg = offs[node], end = offs[node + 1];
    float4 acc0 = {0.f, 0.f, 0.f, 0.f}, acc1 = {0.f, 0.f, 0.f, 0.f};
    float4 acc2 = {0.f, 0.f, 0.f, 0.f}, acc3 = {0.f, 0.f, 0.f, 0.f};
    int e = beg;

    auto body1 = [&](int2 p, float4& acc) {
        float2 r = *((const float2*)(Hin + (size_t)p.x * NFEAT) + q);
        float2 a = __half22float2(((__half2*)&r)[0]);
        float2 b = __half22float2(((__half2*)&r)[1]);
        float w = __int_as_float(p.y);
        acc.x = fmaf(w, a.x, acc.x);
        acc.y = fmaf(w, a.y, acc.y);
        acc.z = fmaf(w, b.x, acc.z);
        acc.w = fmaf(w, b.y, acc.w);
    };

    if (e < end && (e & 1)) {  // align e to even for int4 pairs loads
        body1(pairs[e], acc0);
        ++e;
    }
    for (; e + 4 <= end; e += 4) {  // 4 gathers in flight, 2x int4 edge loads
        int4 pA = *(const int4*)(pairs + e);      // edges e, e+1
        int4 pB = *(const int4*)(pairs + e + 2);  // edges e+2, e+3
        float2 r0 = *((const float2*)(Hin + (size_t)pA.x * NFEAT) + q);
        float2 r1 = *((const float2*)(Hin + (size_t)pA.z * NFEAT) + q);
        float2 r2 = *((const float2*)(Hin + (size_t)pB.x * NFEAT) + q);
        float2 r3 = *((const float2*)(Hin + (size_t)pB.z * NFEAT) + q);
        float w0 = __int_as_float(pA.y), w1 = __int_as_float(pA.w);
        float w2 = __int_as_float(pB.y), w3 = __int_as_float(pB.w);
        float2 a0 = __half22float2(((__half2*)&r0)[0]);
        float2 b0 = __half22float2(((__half2*)&r0)[1]);
        float2 a1 = __half22float2(((__half2*)&r1)[0]);
        float2 b1 = __half22float2(((__half2*)&r1)[1]);
        float2 a2 = __half22float2(((__half2*)&r2)[0]);
        float2 b2 = __half22float2(((__half2*)&r2)[1]);
        float2 a3 = __half22float2(((__half2*)&r3)[0]);
        float2 b3 = __half22float2(((__half2*)&r3)[1]);
        acc0.x = fmaf(w0, a0.x, acc0.x);
        acc0.y = fmaf(w0, a0.y, acc0.y);
        acc0.z = fmaf(w0, b0.x, acc0.z);
        acc0.w = fmaf(w0, b0.y, acc0.w);
        acc1.x = fmaf(w1, a1.x, acc1.x);
        acc1.y = fmaf(w1, a1.y, acc1.y);
        acc1.z = fmaf(w1, b1.x, acc1.z);
        acc1.w = fmaf(w1, b1.y, acc1.w);
        acc2.x = fmaf(w2, a2.x, acc2.x);
        acc2.y = fmaf(w2, a2.y, acc2.y);
        acc2.z = fmaf(w2, b2.x, acc2.z);
        acc2.w = fmaf(w2, b2.y, acc2.w);
        acc3.x = fmaf(w3, a3.x, acc3.x);
        acc3.y = fmaf(w3, a3.y, acc3.y);
        acc3.z = fmaf(w3, b3.x, acc3.z);
        acc3.w = fmaf(w3, b3.y, acc3.w);
    }
    for (; e < end; ++e) body1(pairs[e], acc0);

    acc0.x = (acc0.x + acc1.x) + (acc2.x + acc3.x);
    acc0.y = (acc0.y + acc1.y) + (acc2.y + acc3.y);
    acc0.z = (acc0.z + acc1.z) + (acc2.z + acc3.z);
    acc0.w = (acc0.w + acc1.w) + (acc2.w + acc3.w);
    if constexpr (OUT_HALF) {
        float2 packed;
        ((__half2*)&packed)[0] = __float22half2_rn(make_float2(acc0.x, acc0.y));
        ((__half2*)&packed)[1] = __float22half2_rn(make_float2(acc0.z, acc0.w));
        *((float2*)((__half*)Hout_ + (size_t)node * NFEAT) + q) = packed;
    } else {
        *((float4*)((float*)Hout_ + (size_t)node * NFEAT) + q) = acc0;
    }
}

// ---------------- Dense epilogue: out = H @ W + b (fp32, vector ALU) ----------------

__global__ __launch_bounds__(256) void k_gemm(const float* __restrict__ Hin,
                                              const float* __restrict__ W,
                                              const float* __restrict__ b,
                                              float* __restrict__ out) {
    __shared__ float4 WL[64 * 16];  // 16 KiB
    __shared__ float4 BL[16];
    int t = threadIdx.x;
    const float4* W4 = (const float4*)W;
    for (int k = t; k < 1024; k += 256) WL[k] = W4[k];
    if (t < 16) BL[t] = ((const float4*)b)[t];
    __syncthreads();
    int n = blockIdx.x * 256 + t;  // one node per thread
    if (n >= N_NODES) return;
    const float4* Hrow = (const float4*)(Hin + (size_t)n * NFEAT);
    float4 acc[16];
#pragma unroll
    for (int j = 0; j < 16; ++j) acc[j] = BL[j];
    for (int i4 = 0; i4 < 16; ++i4) {
        float4 h = Hrow[i4];
        const float4* w0 = &WL[(i4 * 4 + 0) * 16];
        const float4* w1 = &WL[(i4 * 4 + 1) * 16];
        const float4* w2 = &WL[(i4 * 4 + 2) * 16];
        const float4* w3 = &WL[(i4 * 4 + 3) * 16];
#pragma unroll
        for (int j = 0; j < 16; ++j) {
            FMA4(acc[j], h.x, w0[j]);
            FMA4(acc[j], h.y, w1[j]);
            FMA4(acc[j], h.z, w2[j]);
            FMA4(acc[j], h.w, w3[j]);
        }
    }
    float4* o = (float4*)(out + (size_t)n * NFEAT);
#pragma unroll
    for (int j = 0; j < 16; ++j) o[j] = acc[j];
}

// ---------------- launch ----------------

extern "C" void kernel_launch(void* const* d_in, const int* in_sizes, int n_in,
                              void* d_out, int out_size, void* d_ws, size_t ws_size,
                              hipStream_t stream) {
    const int* edge_index = (const int*)d_in[0];
    const float* ew = (const float*)d_in[1];
    const float* H = (const float*)d_in[2];
    const float* W = (const float*)d_in[3];
    const float* b = (const float*)d_in[4];
    float* out = (float*)d_out;

    int E = in_sizes[1];              // 800000
    const int* src = edge_index;      // [2,E] row-major: row 0 = src
    const int* dst = edge_index + E;  // row 1 = dst

    // workspace carve-out
    char* ws = (char*)d_ws;
    size_t off = 0;
    auto alloc = [&](size_t bytes) -> void* {
        void* p = ws + off;
        off += (bytes + 255) & ~(size_t)255;
        return p;
    };
    int* bucketCount = (int*)alloc((size_t)NB_BUCKETS * 4);
    int* bucketBase = (int*)alloc(((size_t)NB_BUCKETS + 1) * 4);
    int* bucketCursor = (int*)alloc((size_t)NB_BUCKETS * 4);
    int* offs = (int*)alloc(((size_t)N_NODES + 1) * 4);
    int2* tmp = (int2*)alloc((size_t)E * 8);
    int2* pairs = (int2*)alloc((size_t)E * 8);
    __half* h0 = (__half*)alloc((size_t)N_NODES * NFEAT * 2);  // fp16 ping
    __half* h1 = (__half*)alloc((size_t)N_NODES * NFEAT * 2);  // fp16 pong
    float* bufA = (float*)alloc((size_t)N_NODES * NFEAT * 4);  // fp32 H3

    hipMemsetAsync(bucketCount, 0, (size_t)NB_BUCKETS * 4, stream);

    int nch = (E + CHUNK - 1) / CHUNK;  // 196
    k_bhist<<<nch, 256, 0, stream>>>(dst, E, bucketCount);
    k_bscan<<<1, 256, 0, stream>>>(bucketCount, E, bucketBase, bucketCursor, offs);
    k_bplace<<<nch, 256, 0, stream>>>(src, dst, ew, E, bucketCursor, tmp);
    k_bsort<<<NB_BUCKETS, 256, 0, stream>>>(bucketBase, tmp, pairs, offs);

    // H (fp32) -> h0 (fp16)
    int n4 = N_NODES * NFEAT / 4;  // 800000 float4s
    k_f2h<<<(n4 + 255) / 256, 256, 0, stream>>>(H, h0, n4);

    int nb = (N_NODES + 15) / 16;  // 3125 blocks, 16 nodes/block
    k_spmm4h<true><<<nb, 256, 0, stream>>>(offs, pairs, h0, h1);    // L1: h0->h1
    k_spmm4h<true><<<nb, 256, 0, stream>>>(offs, pairs, h1, h0);    // L2: h1->h0
    k_spmm4h<false><<<nb, 256, 0, stream>>>(offs, pairs, h0, bufA); // L3: h0->fp32

    k_gemm<<<(N_NODES + 255) / 256, 256, 0, stream>>>(bufA, W, b, out);
}